// Round 2
// baseline (41.347 us; speedup 1.0000x reference)
//
#include <hip/hip_runtime.h>

// Problem constants: B=2, C=8, H=256, W=512 -> out [B,C,25,H,W] f32
#define BH 256
#define BW 512
#define BCN 16          // B*C
#define HWSZ (BH * BW)  // 131072

typedef float f4 __attribute__((ext_vector_type(4)));
typedef float f2 __attribute__((ext_vector_type(2)));

__global__ __launch_bounds__(256) void eprod25_kernel(
    const float* __restrict__ e, const float* __restrict__ ce,
    float* __restrict__ out)
{
    const int lane = threadIdx.x & 63;
    const int wv   = threadIdx.x >> 6;
    const int x4   = blockIdx.x * 256 + lane * 4;  // 4 consecutive pixels per thread
    const int y    = blockIdx.y * 4 + wv;
    const int bc   = blockIdx.z;

    const float* __restrict__ ebase = e  + (size_t)bc * HWSZ;
    const float* __restrict__ cbase = ce + (size_t)bc * HWSZ;

    // Register patches: 5 rows x 8 cols (x4-2 .. x4+5), zero-padded.
    float ev[5][8], cv[5][8];
    const bool lok  = (x4 >= 2);        // left float2 fully in-bounds
    const bool rokx = (x4 <= BW - 6);   // right float2 fully in-bounds
#pragma unroll
    for (int di = 0; di < 5; ++di) {
        const int iy = y - 2 + di;
        const bool rk = (unsigned)iy < (unsigned)BH;
        const float* er = ebase + (size_t)iy * BW;
        const float* cr = cbase + (size_t)iy * BW;
        f4 ec = rk ? *(const f4*)(er + x4) : (f4)0.f;
        f4 cc = rk ? *(const f4*)(cr + x4) : (f4)0.f;
        f2 el = (rk && lok)  ? *(const f2*)(er + x4 - 2) : (f2)0.f;
        f2 cl = (rk && lok)  ? *(const f2*)(cr + x4 - 2) : (f2)0.f;
        f2 eg = (rk && rokx) ? *(const f2*)(er + x4 + 4) : (f2)0.f;
        f2 cg = (rk && rokx) ? *(const f2*)(cr + x4 + 4) : (f2)0.f;
        ev[di][0]=el[0]; ev[di][1]=el[1]; ev[di][2]=ec[0]; ev[di][3]=ec[1];
        ev[di][4]=ec[2]; ev[di][5]=ec[3]; ev[di][6]=eg[0]; ev[di][7]=eg[1];
        cv[di][0]=cl[0]; cv[di][1]=cl[1]; cv[di][2]=cc[0]; cv[di][3]=cc[1];
        cv[di][4]=cc[2]; cv[di][5]=cc[3]; cv[di][6]=cg[0]; cv[di][7]=cg[1];
    }

    const bool rok0 = (y >= 1), rok2 = (y <= BH - 2);

    float* __restrict__ obase = out + (size_t)bc * 25 * HWSZ + (size_t)y * BW + x4;

    // first-occurrence argmax semantics (strict >)
    auto sel2 = [](float a0, float a1, float c0, float c1) {
        return (c1 > c0) ? a1 : a0;
    };
    auto sel3 = [](float a0, float a1, float a2, float c0, float c1, float c2) {
        float best = c0, a = a0;
        if (c1 > best) { best = c1; a = a1; }
        if (c2 > best) { a = a2; }
        return a;
    };

    // Build one float4 (4 pixels) per channel and store immediately (keeps VGPRs low).
    auto st4 = [&](int k, auto f) {
        f4 v;
        v[0] = f(0); v[1] = f(1); v[2] = f(2); v[3] = f(3);
        __builtin_nontemporal_store(v, reinterpret_cast<f4*>(obase + (size_t)k * HWSZ));
    };

    // Patch accessors for pixel p (pixel x = x4+p; patch col c in 0..4 -> ev[.][p+c])
#define PE(di, c) ev[di][p + (c)]
#define PC(di, c) cv[di][p + (c)]
#define MASKS \
    const bool cok0 = (x4 + p >= 1); \
    const bool cok2 = (x4 + p <= BW - 2); \
    const bool m00 = rok0 && cok0; const bool m01 = rok0; const bool m02 = rok0 && cok2; \
    const bool m10 = cok0; const bool m12 = cok2; \
    const bool m20 = rok2 && cok0; const bool m21 = rok2; const bool m22 = rok2 && cok2; \
    (void)m00; (void)m01; (void)m02; (void)m10; (void)m12; (void)m20; (void)m21; (void)m22;
#define MVE(di, c, m) ((m) ? PE(di, c) : 0.f)
#define MVC(di, c, m) ((m) ? PC(di, c) : 0.f)

    // Row 0
    st4(0, [&](int p) { MASKS return PE(1,1) * MVE(0,0,m00); });                       // e00
    st4(1, [&](int p) { MASKS return sel2(PE(1,1)*MVE(0,1,m00), PE(1,2)*MVE(0,1,m01),
                                          PC(1,1)*MVC(0,1,m00), PC(1,2)*MVC(0,1,m01)); });  // e01
    st4(2, [&](int p) { MASKS return sel3(PE(1,1)*MVE(0,2,m00), PE(1,2)*MVE(0,2,m01), PE(1,3)*MVE(0,2,m02),
                                          PC(1,1)*MVC(0,2,m00), PC(1,2)*MVC(0,2,m01), PC(1,3)*MVC(0,2,m02)); }); // e02
    st4(3, [&](int p) { MASKS return sel2(PE(1,2)*MVE(0,3,m01), PE(1,3)*MVE(0,3,m02),
                                          PC(1,2)*MVC(0,3,m01), PC(1,3)*MVC(0,3,m02)); });  // e03
    st4(4, [&](int p) { MASKS return PE(1,3) * MVE(0,4,m02); });                       // e04

    // Row 1
    st4(5, [&](int p) { MASKS return sel2(PE(1,1)*MVE(1,0,m00), PE(2,1)*MVE(1,0,m10),
                                          PC(1,1)*MVC(1,0,m00), PC(2,1)*MVC(1,0,m10)); });  // e10
    st4(6, [&](int p) { return PE(1,1); });   // E(0)
    st4(7, [&](int p) { return PE(1,2); });   // E(1)
    st4(8, [&](int p) { return PE(1,3); });   // E(2)
    st4(9, [&](int p) { MASKS return sel2(PE(1,3)*MVE(1,4,m02), PE(2,3)*MVE(1,4,m12),
                                          PC(1,3)*MVC(1,4,m02), PC(2,3)*MVC(1,4,m12)); });  // e14

    // Row 2
    st4(10, [&](int p) { MASKS return sel3(PE(1,1)*MVE(2,0,m00), PE(2,1)*MVE(2,0,m10), PE(3,1)*MVE(2,0,m20),
                                           PC(1,1)*MVC(2,0,m00), PC(2,1)*MVC(2,0,m10), PC(3,1)*MVC(2,0,m20)); }); // e20
    st4(11, [&](int p) { return PE(2,1); });  // E(3)
    st4(12, [&](int p) { return 1.f; });      // E(4) = ones
    st4(13, [&](int p) { return PE(2,3); });  // E(5)
    // e24: middle c-candidate uses Cp(3,1,2)=cv[2][2] masked m12 — faithful to source bug
    st4(14, [&](int p) { MASKS return sel3(PE(1,3)*MVE(2,4,m02), PE(2,3)*MVE(2,4,m12), PE(3,3)*MVE(2,4,m22),
                                           PC(1,3)*MVC(2,4,m02), PC(2,3)*MVC(2,2,m12), PC(3,3)*MVC(2,4,m22)); }); // e24

    // Row 3
    st4(15, [&](int p) { MASKS return sel2(PE(2,1)*MVE(3,0,m10), PE(3,1)*MVE(3,0,m20),
                                           PC(2,1)*MVC(3,0,m10), PC(3,1)*MVC(3,0,m20)); }); // e30
    st4(16, [&](int p) { return PE(3,1); });  // E(6)
    st4(17, [&](int p) { return PE(3,2); });  // E(7)
    st4(18, [&](int p) { return PE(3,3); });  // E(8)
    st4(19, [&](int p) { MASKS return sel2(PE(2,3)*MVE(3,4,m12), PE(3,3)*MVE(3,4,m22),
                                           PC(2,3)*MVC(3,4,m12), PC(3,3)*MVC(3,4,m22)); }); // e34

    // Row 4
    st4(20, [&](int p) { MASKS return PE(3,1) * MVE(4,0,m20); });                      // e40
    st4(21, [&](int p) { MASKS return sel2(PE(3,1)*MVE(4,1,m20), PE(3,2)*MVE(4,1,m21),
                                           PC(3,1)*MVC(4,1,m20), PC(3,2)*MVC(4,1,m21)); }); // e41
    st4(22, [&](int p) { MASKS return sel3(PE(3,1)*MVE(4,2,m20), PE(3,2)*MVE(4,2,m21), PE(3,3)*MVE(4,2,m22),
                                           PC(3,1)*MVC(4,2,m20), PC(3,2)*MVC(4,2,m21), PC(3,3)*MVC(4,2,m22)); }); // e42
    st4(23, [&](int p) { MASKS return sel2(PE(3,2)*MVE(4,3,m21), PE(3,3)*MVE(4,3,m22),
                                           PC(3,2)*MVC(4,3,m21), PC(3,3)*MVC(4,3,m22)); }); // e43
    st4(24, [&](int p) { MASKS return PE(3,3) * MVE(4,4,m22); });                      // e44

#undef PE
#undef PC
#undef MASKS
#undef MVE
#undef MVC
}

extern "C" void kernel_launch(void* const* d_in, const int* in_sizes, int n_in,
                              void* d_out, int out_size, void* d_ws, size_t ws_size,
                              hipStream_t stream) {
    const float* e  = (const float*)d_in[0];
    const float* ce = (const float*)d_in[1];
    float* out = (float*)d_out;

    dim3 grid(BW / 256, BH / 4, BCN);   // (2, 64, 16)
    dim3 block(256);
    eprod25_kernel<<<grid, block, 0, stream>>>(e, ce, out);
}